// Round 1
// baseline (217.884 us; speedup 1.0000x reference)
//
#include <hip/hip_runtime.h>
#include <hip/hip_bf16.h>

#define S_LEN 2048
#define NH 16
#define HD 64
#define DM 1024
#define BATCH 2
#define M_ROWS (BATCH * S_LEN)  // 4096

typedef float f32x4 __attribute__((ext_vector_type(4)));
typedef __bf16 bf16x8 __attribute__((ext_vector_type(8)));
typedef short short8 __attribute__((ext_vector_type(8)));

__device__ __forceinline__ unsigned short f2bf(float f) {
  unsigned u = __builtin_bit_cast(unsigned, f);
  u += 0x7FFFu + ((u >> 16) & 1u);
  return (unsigned short)(u >> 16);
}

__device__ __forceinline__ f32x4 mfma16(bf16x8 a, bf16x8 b, f32x4 c) {
  return __builtin_amdgcn_mfma_f32_16x16x32_bf16(a, b, c, 0, 0, 0);
}

__device__ __forceinline__ void gload_lds16(const void* g, void* l) {
  __builtin_amdgcn_global_load_lds(
      (const __attribute__((address_space(1))) void*)g,
      (__attribute__((address_space(3))) void*)l, 16, 0, 0);
}

// ---------------- cast x -> bf16 (vectorized) ----------------
__global__ __launch_bounds__(256) void cast_bf16_kernel(
    const float* __restrict__ in, unsigned short* __restrict__ out) {
  int i = blockIdx.x * 256 + threadIdx.x;  // each handles 8 elems
  const float4* p = (const float4*)in;
  float4 f0 = p[i * 2], f1 = p[i * 2 + 1];
  short8 o;
  o[0] = (short)f2bf(f0.x); o[1] = (short)f2bf(f0.y);
  o[2] = (short)f2bf(f0.z); o[3] = (short)f2bf(f0.w);
  o[4] = (short)f2bf(f1.x); o[5] = (short)f2bf(f1.y);
  o[6] = (short)f2bf(f1.z); o[7] = (short)f2bf(f1.w);
  ((short8*)out)[i] = o;
}

// ---------------- transpose + cast weights: Wt[n][k] = bf16(W[k][n]) ----------------
__global__ __launch_bounds__(256) void transpose_cast_kernel(
    const float* __restrict__ W0, const float* __restrict__ W1,
    const float* __restrict__ W2, const float* __restrict__ W3,
    unsigned short* __restrict__ out) {
  int z = blockIdx.z;
  const float* W = (z == 0) ? W0 : (z == 1) ? W1 : (z == 2) ? W2 : W3;
  __shared__ float tile[32][33];
  int tx = threadIdx.x & 31, ty = threadIdx.x >> 5;  // 32 x 8
  int bx = blockIdx.x * 32, by = blockIdx.y * 32;
#pragma unroll
  for (int i = 0; i < 4; ++i)
    tile[ty + i * 8][tx] = W[(size_t)(by + ty + i * 8) * DM + bx + tx];
  __syncthreads();
  unsigned short* o = out + (size_t)z * DM * DM;
#pragma unroll
  for (int i = 0; i < 4; ++i)
    o[(size_t)(bx + ty + i * 8) * DM + by + tx] = f2bf(tile[tx][ty + i * 8]);
}

// ---------------- GEMM: C[m][n] = sum_k A[m][k] * Bt[n][k]  (m97 structure) ----------------
// MODE 0: bf16 out to 3 stacked buffers of 4Mi elems each (QKV fused, N=3072), bias0..2
// MODE 1: f32 out (single buffer), bias0
template <int MODE>
__global__ __launch_bounds__(256) void gemm_bt_kernel(
    const unsigned short* __restrict__ A, const unsigned short* __restrict__ Bt,
    void* __restrict__ Cptr, const float* __restrict__ bias0,
    const float* __restrict__ bias1, const float* __restrict__ bias2,
    int M, int N, int K) {
  __shared__ __align__(16) unsigned short As[128 * 32];
  __shared__ __align__(16) unsigned short Bs[128 * 32];
  const int t = threadIdx.x, lane = t & 63;
  const int wid = t >> 6, wr = wid >> 1, wc = wid & 1;
  const int r16 = lane & 15, g = lane >> 4;
  const int m0 = blockIdx.y * 128, n0 = blockIdx.x * 128;

  f32x4 acc[4][4] = {};

  for (int k0 = 0; k0 < K; k0 += 32) {
#pragma unroll
    for (int i = 0; i < 2; ++i) {
      int idx = t + i * 256;
      int row = idx >> 2, c8 = (idx & 3) << 3;
      gload_lds16(A + (size_t)(m0 + row) * K + k0 + c8, &As[idx * 8]);
      gload_lds16(Bt + (size_t)(n0 + row) * K + k0 + c8, &Bs[idx * 8]);
    }
    __syncthreads();
    bf16x8 af[4], bfr[4];
#pragma unroll
    for (int mi = 0; mi < 4; ++mi)
      af[mi] = *(const bf16x8*)&As[(wr * 64 + mi * 16 + r16) * 32 + g * 8];
#pragma unroll
    for (int ni = 0; ni < 4; ++ni)
      bfr[ni] = *(const bf16x8*)&Bs[(wc * 64 + ni * 16 + r16) * 32 + g * 8];
#pragma unroll
    for (int mi = 0; mi < 4; ++mi)
#pragma unroll
      for (int ni = 0; ni < 4; ++ni)
        acc[mi][ni] = mfma16(af[mi], bfr[ni], acc[mi][ni]);
    __syncthreads();
  }

  if (MODE == 0) {
    unsigned short* Cb = (unsigned short*)Cptr;
#pragma unroll
    for (int ni = 0; ni < 4; ++ni) {
      int col = n0 + wc * 64 + ni * 16 + r16;
      int buf = col >> 10, cn = col & 1023;
      const float* bp = (buf == 0) ? bias0 : (buf == 1) ? bias1 : bias2;
      float bv = bp[cn];
#pragma unroll
      for (int mi = 0; mi < 4; ++mi) {
        int rowb = m0 + wr * 64 + mi * 16 + 4 * g;
#pragma unroll
        for (int j = 0; j < 4; ++j)
          Cb[(size_t)buf * 4194304u + (size_t)(rowb + j) * 1024 + cn] =
              f2bf(acc[mi][ni][j] + bv);
      }
    }
  } else {
    float* Cf = (float*)Cptr;
#pragma unroll
    for (int ni = 0; ni < 4; ++ni) {
      int col = n0 + wc * 64 + ni * 16 + r16;
      float bv = bias0[col];
#pragma unroll
      for (int mi = 0; mi < 4; ++mi) {
        int rowb = m0 + wr * 64 + mi * 16 + 4 * g;
#pragma unroll
        for (int j = 0; j < 4; ++j)
          Cf[(size_t)(rowb + j) * N + col] = acc[mi][ni][j] + bv;
      }
    }
  }
}

// ---------------- flash attention (causal, online softmax) ----------------
// grid (S/64, H, B); 4 waves; wave w owns q rows [q0+w*16, +16)
// Swapped QK^T: St = K*Q^T so lane owns q-row r16. O accum in regs.
__global__ __launch_bounds__(256) void attn_kernel(
    const unsigned short* __restrict__ Qm, const unsigned short* __restrict__ Km,
    const unsigned short* __restrict__ Vm, unsigned short* __restrict__ Om) {
  const int t = threadIdx.x, lane = t & 63, w = t >> 6;
  const int r16 = lane & 15, g = lane >> 4;
  const int qt = blockIdx.x, h = blockIdx.y, b = blockIdx.z;
  const int q0 = qt * 64;
  __shared__ __align__(16) unsigned short Vt[64 * 88];  // [d][kv], stride 88 (pad)

  const unsigned short* Qp =
      Qm + (size_t)(b * S_LEN + q0 + w * 16 + r16) * DM + h * HD + g * 8;
  bf16x8 qf0 = *(const bf16x8*)Qp;
  bf16x8 qf1 = *(const bf16x8*)(Qp + 32);

  f32x4 oacc[4] = {};
  float mrun = -1e30f, lrun = 0.f;
  const int qg = q0 + w * 16 + r16;  // this lane's q row (St layout)

  for (int kt = 0; kt <= qt; ++kt) {
    const int kv0 = kt * 64;
    __syncthreads();  // protect Vt from previous iteration's readers
    // stage V transposed: Vt[d][kv]
#pragma unroll
    for (int i = 0; i < 2; ++i) {
      int idx = t + i * 256;
      int r = idx >> 3, c = (idx & 7) << 3;
      short8 vv = *(const short8*)(Vm + (size_t)(b * S_LEN + kv0 + r) * DM + h * HD + c);
#pragma unroll
      for (int e = 0; e < 8; ++e) Vt[(c + e) * 88 + r] = (unsigned short)vv[e];
    }
    __syncthreads();

    // St = K * Q^T : lane holds St[kv = kv0+ni*16+4g+j][q = r16]
    f32x4 st[4] = {};
    const unsigned short* Kp =
        Km + (size_t)(b * S_LEN + kv0 + r16) * DM + h * HD + g * 8;
#pragma unroll
    for (int ni = 0; ni < 4; ++ni) {
      bf16x8 kf0 = *(const bf16x8*)(Kp + (size_t)ni * 16 * DM);
      bf16x8 kf1 = *(const bf16x8*)(Kp + (size_t)ni * 16 * DM + 32);
      st[ni] = mfma16(kf0, qf0, st[ni]);
      st[ni] = mfma16(kf1, qf1, st[ni]);
    }

    // mask + scale (faithful: kv<=q -> s/8, else -10000)
    float p[4][4];
    float tmax = -1e30f;
#pragma unroll
    for (int ni = 0; ni < 4; ++ni)
#pragma unroll
      for (int j = 0; j < 4; ++j) {
        int kv = kv0 + ni * 16 + 4 * g + j;
        float s = (kv <= qg) ? st[ni][j] * 0.125f : -10000.f;
        p[ni][j] = s;
        tmax = fmaxf(tmax, s);
      }
    tmax = fmaxf(tmax, __shfl_xor(tmax, 16));
    tmax = fmaxf(tmax, __shfl_xor(tmax, 32));
    float mnew = fmaxf(mrun, tmax);
    float corr = __expf(mrun - mnew);
    float rsum = 0.f;
#pragma unroll
    for (int ni = 0; ni < 4; ++ni)
#pragma unroll
      for (int j = 0; j < 4; ++j) {
        p[ni][j] = __expf(p[ni][j] - mnew);
        rsum += p[ni][j];
      }
    rsum += __shfl_xor(rsum, 16);
    rsum += __shfl_xor(rsum, 32);
    lrun = lrun * corr + rsum;
    mrun = mnew;

    // rescale O (O layout: lane owns q = 4g+j)
    float corrO[4];
#pragma unroll
    for (int j = 0; j < 4; ++j) corrO[j] = __shfl(corr, 4 * g + j);
#pragma unroll
    for (int di = 0; di < 4; ++di)
#pragma unroll
      for (int j = 0; j < 4; ++j) oacc[di][j] *= corrO[j];

    // pack P to bf16 and redistribute to PV A-fragment layout
    unsigned pk[4][2];
#pragma unroll
    for (int ni = 0; ni < 4; ++ni) {
      pk[ni][0] = (unsigned)f2bf(p[ni][0]) | ((unsigned)f2bf(p[ni][1]) << 16);
      pk[ni][1] = (unsigned)f2bf(p[ni][2]) | ((unsigned)f2bf(p[ni][3]) << 16);
    }
#pragma unroll
    for (int kh = 0; kh < 2; ++kh) {
      int srcA = ((g & 1) << 5) + r16;
      unsigned a0 = (unsigned)__shfl((int)pk[kh * 2][0], srcA);
      unsigned b0 = (unsigned)__shfl((int)pk[kh * 2 + 1][0], srcA);
      unsigned a1 = (unsigned)__shfl((int)pk[kh * 2][1], srcA);
      unsigned b1 = (unsigned)__shfl((int)pk[kh * 2 + 1][1], srcA);
      unsigned a2 = (unsigned)__shfl((int)pk[kh * 2][0], srcA + 16);
      unsigned b2 = (unsigned)__shfl((int)pk[kh * 2 + 1][0], srcA + 16);
      unsigned a3 = (unsigned)__shfl((int)pk[kh * 2][1], srcA + 16);
      unsigned b3 = (unsigned)__shfl((int)pk[kh * 2 + 1][1], srcA + 16);
      bool hi = (g & 2) != 0;
      union { unsigned u[4]; bf16x8 v; } pu;
      pu.u[0] = hi ? b0 : a0;
      pu.u[1] = hi ? b1 : a1;
      pu.u[2] = hi ? b2 : a2;
      pu.u[3] = hi ? b3 : a3;
#pragma unroll
      for (int di = 0; di < 4; ++di) {
        bf16x8 vf = *(const bf16x8*)&Vt[(r16 + 16 * di) * 88 + kh * 32 + g * 8];
        oacc[di] = mfma16(pu.v, vf, oacc[di]);
      }
    }
  }

  float linv = 1.0f / lrun;
  float linvO[4];
#pragma unroll
  for (int j = 0; j < 4; ++j) linvO[j] = __shfl(linv, 4 * g + j);
#pragma unroll
  for (int di = 0; di < 4; ++di)
#pragma unroll
    for (int j = 0; j < 4; ++j) {
      int qq = q0 + w * 16 + 4 * g + j;
      Om[(size_t)(b * S_LEN + qq) * DM + h * HD + di * 16 + r16] =
          f2bf(oacc[di][j] * linvO[j]);
    }
}

extern "C" void kernel_launch(void* const* d_in, const int* in_sizes, int n_in,
                              void* d_out, int out_size, void* d_ws, size_t ws_size,
                              hipStream_t stream) {
  (void)in_sizes; (void)n_in; (void)out_size; (void)ws_size;
  const float* x  = (const float*)d_in[0];
  const float* WQ = (const float*)d_in[1];
  const float* WK = (const float*)d_in[2];
  const float* WV = (const float*)d_in[3];
  const float* WO = (const float*)d_in[4];
  const float* bQ = (const float*)d_in[5];
  const float* bK = (const float*)d_in[6];
  const float* bV = (const float*)d_in[7];
  const float* bO = (const float*)d_in[8];

  char* ws = (char*)d_ws;
  unsigned short* xb  = (unsigned short*)(ws);                       // 8 MiB
  unsigned short* wt  = (unsigned short*)(ws + (8u << 20));          // 8 MiB (Wq|Wk|Wv|Wo)^T
  unsigned short* qb  = (unsigned short*)(ws + (16u << 20));         // 8 MiB
  unsigned short* hsb = (unsigned short*)(ws + (40u << 20));         // 8 MiB
  // kb = qb + 4Mi elems, vb = qb + 8Mi elems (contiguous)

  cast_bf16_kernel<<<2048, 256, 0, stream>>>(x, xb);
  transpose_cast_kernel<<<dim3(32, 32, 4), 256, 0, stream>>>(WQ, WK, WV, WO, wt);
  // fused QKV projection: N = 3072
  gemm_bt_kernel<0><<<dim3(24, 32), 256, 0, stream>>>(
      xb, wt, (void*)qb, bQ, bK, bV, M_ROWS, 3072, DM);
  attn_kernel<<<dim3(S_LEN / 64, NH, BATCH), 256, 0, stream>>>(
      qb, qb + 4194304u, qb + 8388608u, hsb);
  // output projection: f32 out
  gemm_bt_kernel<1><<<dim3(8, 32), 256, 0, stream>>>(
      hsb, wt + 3u * 1048576u, d_out, bO, nullptr, nullptr, M_ROWS, DM, DM);
}

// Round 2
// 141.843 us; speedup vs baseline: 1.5361x; 1.5361x over previous
//
#include <hip/hip_runtime.h>
#include <hip/hip_bf16.h>

#define S_LEN 2048
#define NH 16
#define HD 64
#define DM 1024
#define BATCH 2
#define M_ROWS (BATCH * S_LEN)  // 4096

typedef float f32x4 __attribute__((ext_vector_type(4)));
typedef __bf16 bf16x8 __attribute__((ext_vector_type(8)));
typedef short short8 __attribute__((ext_vector_type(8)));

__device__ __forceinline__ unsigned short f2bf(float f) {
  unsigned u = __builtin_bit_cast(unsigned, f);
  u += 0x7FFFu + ((u >> 16) & 1u);
  return (unsigned short)(u >> 16);
}

__device__ __forceinline__ f32x4 mfma16(bf16x8 a, bf16x8 b, f32x4 c) {
  return __builtin_amdgcn_mfma_f32_16x16x32_bf16(a, b, c, 0, 0, 0);
}

__device__ __forceinline__ void gload_lds16(const void* g, void* l) {
  __builtin_amdgcn_global_load_lds(
      (const __attribute__((address_space(1))) void*)g,
      (__attribute__((address_space(3))) void*)l, 16, 0, 0);
}

// ---------------- cast x -> bf16 (vectorized) ----------------
__global__ __launch_bounds__(256) void cast_bf16_kernel(
    const float* __restrict__ in, unsigned short* __restrict__ out) {
  int i = blockIdx.x * 256 + threadIdx.x;  // each handles 8 elems
  const float4* p = (const float4*)in;
  float4 f0 = p[i * 2], f1 = p[i * 2 + 1];
  short8 o;
  o[0] = (short)f2bf(f0.x); o[1] = (short)f2bf(f0.y);
  o[2] = (short)f2bf(f0.z); o[3] = (short)f2bf(f0.w);
  o[4] = (short)f2bf(f1.x); o[5] = (short)f2bf(f1.y);
  o[6] = (short)f2bf(f1.z); o[7] = (short)f2bf(f1.w);
  ((short8*)out)[i] = o;
}

// ---------------- transpose + cast weights: Wt[n][k] = bf16(W[k][n]) ----------------
__global__ __launch_bounds__(256) void transpose_cast_kernel(
    const float* __restrict__ W0, const float* __restrict__ W1,
    const float* __restrict__ W2, const float* __restrict__ W3,
    unsigned short* __restrict__ out) {
  int z = blockIdx.z;
  const float* W = (z == 0) ? W0 : (z == 1) ? W1 : (z == 2) ? W2 : W3;
  __shared__ float tile[32][33];
  int tx = threadIdx.x & 31, ty = threadIdx.x >> 5;  // 32 x 8
  int bx = blockIdx.x * 32, by = blockIdx.y * 32;
#pragma unroll
  for (int i = 0; i < 4; ++i)
    tile[ty + i * 8][tx] = W[(size_t)(by + ty + i * 8) * DM + bx + tx];
  __syncthreads();
  unsigned short* o = out + (size_t)z * DM * DM;
#pragma unroll
  for (int i = 0; i < 4; ++i)
    o[(size_t)(bx + ty + i * 8) * DM + by + tx] = f2bf(tile[tx][ty + i * 8]);
}

// ---------------- GEMM: C[m][n] = sum_k A[m][k] * Bt[n][k]  (m97 structure) ----------------
template <int MODE>
__global__ __launch_bounds__(256) void gemm_bt_kernel(
    const unsigned short* __restrict__ A, const unsigned short* __restrict__ Bt,
    void* __restrict__ Cptr, const float* __restrict__ bias0,
    const float* __restrict__ bias1, const float* __restrict__ bias2,
    int M, int N, int K) {
  __shared__ __align__(16) unsigned short As[128 * 32];
  __shared__ __align__(16) unsigned short Bs[128 * 32];
  const int t = threadIdx.x, lane = t & 63;
  const int wid = t >> 6, wr = wid >> 1, wc = wid & 1;
  const int r16 = lane & 15, g = lane >> 4;
  const int m0 = blockIdx.y * 128, n0 = blockIdx.x * 128;

  f32x4 acc[4][4] = {};

  for (int k0 = 0; k0 < K; k0 += 32) {
#pragma unroll
    for (int i = 0; i < 2; ++i) {
      int idx = t + i * 256;
      int row = idx >> 2, c8 = (idx & 3) << 3;
      gload_lds16(A + (size_t)(m0 + row) * K + k0 + c8, &As[idx * 8]);
      gload_lds16(Bt + (size_t)(n0 + row) * K + k0 + c8, &Bs[idx * 8]);
    }
    __syncthreads();
    bf16x8 af[4], bfr[4];
#pragma unroll
    for (int mi = 0; mi < 4; ++mi)
      af[mi] = *(const bf16x8*)&As[(wr * 64 + mi * 16 + r16) * 32 + g * 8];
#pragma unroll
    for (int ni = 0; ni < 4; ++ni)
      bfr[ni] = *(const bf16x8*)&Bs[(wc * 64 + ni * 16 + r16) * 32 + g * 8];
#pragma unroll
    for (int mi = 0; mi < 4; ++mi)
#pragma unroll
      for (int ni = 0; ni < 4; ++ni)
        acc[mi][ni] = mfma16(af[mi], bfr[ni], acc[mi][ni]);
    __syncthreads();
  }

  if (MODE == 0) {
    unsigned short* Cb = (unsigned short*)Cptr;
#pragma unroll
    for (int ni = 0; ni < 4; ++ni) {
      int col = n0 + wc * 64 + ni * 16 + r16;
      int buf = col >> 10, cn = col & 1023;
      const float* bp = (buf == 0) ? bias0 : (buf == 1) ? bias1 : bias2;
      float bv = bp[cn];
#pragma unroll
      for (int mi = 0; mi < 4; ++mi) {
        int rowb = m0 + wr * 64 + mi * 16 + 4 * g;
#pragma unroll
        for (int j = 0; j < 4; ++j)
          Cb[(size_t)buf * 4194304u + (size_t)(rowb + j) * 1024 + cn] =
              f2bf(acc[mi][ni][j] + bv);
      }
    }
  } else {
    float* Cf = (float*)Cptr;
#pragma unroll
    for (int ni = 0; ni < 4; ++ni) {
      int col = n0 + wc * 64 + ni * 16 + r16;
      float bv = bias0[col];
#pragma unroll
      for (int mi = 0; mi < 4; ++mi) {
        int rowb = m0 + wr * 64 + mi * 16 + 4 * g;
#pragma unroll
        for (int j = 0; j < 4; ++j)
          Cf[(size_t)(rowb + j) * N + col] = acc[mi][ni][j] + bv;
      }
    }
  }
}

// ---------------- V transpose: V[b*S+s][h*64+d] -> Vt[(bh*64+d)*S + s] ----------------
__global__ __launch_bounds__(256) void vtrans_kernel(
    const unsigned short* __restrict__ V, unsigned short* __restrict__ Vt) {
  __shared__ __align__(16) unsigned short tile[128 * 72];
  const int t = threadIdx.x;
  const int s0 = blockIdx.x * 128;
  const int bh = blockIdx.y, b = bh >> 4, h = bh & 15;
#pragma unroll
  for (int p = 0; p < 4; ++p) {
    int idx = p * 256 + t;  // 0..1023: 128 s x 8 chunks
    int sl = idx >> 3, c8 = (idx & 7) * 8;
    *(short8*)&tile[sl * 72 + c8] =
        *(const short8*)(V + (size_t)(b * S_LEN + s0 + sl) * DM + h * HD + c8);
  }
  __syncthreads();
#pragma unroll
  for (int p = 0; p < 4; ++p) {
    int idx = p * 256 + t;  // 64 d x 16 s-chunks
    int dlow = idx & 7, sc = (idx >> 3) & 15, dh = idx >> 7;
    int d = dh * 8 + dlow, s8 = sc * 8;
    short8 o;
#pragma unroll
    for (int e = 0; e < 8; ++e) o[e] = (short)tile[(s8 + e) * 72 + d];
    *(short8*)(Vt + (size_t)(bh * HD + d) * S_LEN + s0 + s8) = o;
  }
}

// ---------------- flash attention (causal, online softmax, O^T formulation) ----------------
// grid (16, H, B); block = 4 waves, handles q-tiles {bx, 31-bx} sequentially (balance).
// Wave w owns q rows [q0+w*16, +16). Swapped QK^T: St[kv][q], lane col q=r16.
// PV: O^T[d][q] = V^T[d][kv] * P^T[kv][q] -> rescale/linv need NO shuffles.
// K and V^T tiles staged via global_load_lds with XOR src-swizzle (linear dest).
__global__ __launch_bounds__(256) void attn_kernel(
    const unsigned short* __restrict__ Qm, const unsigned short* __restrict__ Km,
    const unsigned short* __restrict__ VtG, unsigned short* __restrict__ Om) {
  const int t = threadIdx.x, lane = t & 63, w = t >> 6;
  const int r16 = lane & 15, g = lane >> 4;
  const int h = blockIdx.y, b = blockIdx.z;
  __shared__ __align__(16) unsigned short Ks[2][64 * 64];
  __shared__ __align__(16) unsigned short Vs[2][64 * 64];
  __shared__ __align__(16) unsigned short Pl[4 * 16 * 72];

  const unsigned short* Kbase = Km + (size_t)(b * S_LEN) * DM + h * HD;
  const unsigned short* Vbase = VtG + (size_t)((b * NH + h) * HD) * S_LEN;

  // staging chunk assignments: chunk n (0..511): row n>>3, lds chunk n&7,
  // global chunk (n&7)^(row&7)  [inverse-swizzled source, linear LDS dest]
  const int n1 = t, n2 = t + 256;
  const int r1 = n1 >> 3, c1 = ((n1 & 7) ^ (r1 & 7)) * 8;
  const int r2 = n2 >> 3, c2 = ((n2 & 7) ^ (r2 & 7)) * 8;
  const int sx = r16 & 7;  // read-side XOR

  for (int half = 0; half < 2; ++half) {
    const int qt = half ? (31 - (int)blockIdx.x) : (int)blockIdx.x;
    const int q0 = qt * 64;
    const int qloc = w * 16 + r16;  // local q row within tile (this lane's q)

    const unsigned short* Qp = Qm + (size_t)(b * S_LEN + q0 + qloc) * DM + h * HD;
    bf16x8 qf0 = *(const bf16x8*)(Qp + g * 8);
    bf16x8 qf1 = *(const bf16x8*)(Qp + 32 + g * 8);

    f32x4 oacc[4] = {};
    float mrun = -1e30f, lrun = 0.f;

    const int ntk = qt + 1;
    // prologue: stage kt=0 into buf 0
    gload_lds16(Kbase + (size_t)r1 * DM + c1, &Ks[0][n1 * 8]);
    gload_lds16(Kbase + (size_t)r2 * DM + c2, &Ks[0][n2 * 8]);
    gload_lds16(Vbase + (size_t)r1 * S_LEN + c1, &Vs[0][n1 * 8]);
    gload_lds16(Vbase + (size_t)r2 * S_LEN + c2, &Vs[0][n2 * 8]);
    __syncthreads();
    int cur = 0;

    for (int kt = 0; kt < ntk; ++kt) {
      if (kt + 1 < ntk) {
        const int kv1 = (kt + 1) * 64;
        gload_lds16(Kbase + (size_t)(kv1 + r1) * DM + c1, &Ks[cur ^ 1][n1 * 8]);
        gload_lds16(Kbase + (size_t)(kv1 + r2) * DM + c2, &Ks[cur ^ 1][n2 * 8]);
        gload_lds16(Vbase + (size_t)r1 * S_LEN + kv1 + c1, &Vs[cur ^ 1][n1 * 8]);
        gload_lds16(Vbase + (size_t)r2 * S_LEN + kv1 + c2, &Vs[cur ^ 1][n2 * 8]);
      }

      // QK^T: St[kv = ni*16+4g+j][q = r16]
      f32x4 st[4];
#pragma unroll
      for (int ni = 0; ni < 4; ++ni) {
        int row = ni * 16 + r16;
        f32x4 a0 = {};
        bf16x8 kf0 = *(const bf16x8*)&Ks[cur][row * 64 + ((g ^ sx) * 8)];
        bf16x8 kf1 = *(const bf16x8*)&Ks[cur][row * 64 + (((4 + g) ^ sx) * 8)];
        a0 = mfma16(kf0, qf0, a0);
        a0 = mfma16(kf1, qf1, a0);
        st[ni] = a0;
      }

      // softmax (online) — lane owns q = r16 (4 g-copies identical after reduce)
      float p[4][4];
      float tmax = -1e30f;
      if (kt == qt) {
#pragma unroll
        for (int ni = 0; ni < 4; ++ni)
#pragma unroll
          for (int j = 0; j < 4; ++j) {
            int kvl = ni * 16 + 4 * g + j;
            float s = (kvl <= qloc) ? st[ni][j] * 0.125f : -10000.f;
            p[ni][j] = s;
            tmax = fmaxf(tmax, s);
          }
      } else {
#pragma unroll
        for (int ni = 0; ni < 4; ++ni)
#pragma unroll
          for (int j = 0; j < 4; ++j) {
            float s = st[ni][j] * 0.125f;
            p[ni][j] = s;
            tmax = fmaxf(tmax, s);
          }
      }
      tmax = fmaxf(tmax, __shfl_xor(tmax, 16));
      tmax = fmaxf(tmax, __shfl_xor(tmax, 32));
      float mnew = fmaxf(mrun, tmax);
      float corr = __expf(mrun - mnew);
      float rsum = 0.f;
#pragma unroll
      for (int ni = 0; ni < 4; ++ni)
#pragma unroll
        for (int j = 0; j < 4; ++j) {
          p[ni][j] = __expf(p[ni][j] - mnew);
          rsum += p[ni][j];
        }
      rsum += __shfl_xor(rsum, 16);
      rsum += __shfl_xor(rsum, 32);
      lrun = lrun * corr + rsum;
      mrun = mnew;

      // rescale O^T (all of this lane's acc share q=r16 -> scalar multiply)
#pragma unroll
      for (int di = 0; di < 4; ++di)
#pragma unroll
        for (int j = 0; j < 4; ++j) oacc[di][j] *= corr;

      // P -> per-wave LDS (padded stride 72), then read as B-fragments
      unsigned* Pw32 = (unsigned*)&Pl[w * 1152];
#pragma unroll
      for (int ni = 0; ni < 4; ++ni) {
        unsigned lo = (unsigned)f2bf(p[ni][0]) | ((unsigned)f2bf(p[ni][1]) << 16);
        unsigned hi2 = (unsigned)f2bf(p[ni][2]) | ((unsigned)f2bf(p[ni][3]) << 16);
        Pw32[r16 * 36 + ni * 8 + 2 * g + 0] = lo;
        Pw32[r16 * 36 + ni * 8 + 2 * g + 1] = hi2;
      }
      bf16x8 pf0 = *(const bf16x8*)&Pl[w * 1152 + r16 * 72 + g * 8];
      bf16x8 pf1 = *(const bf16x8*)&Pl[w * 1152 + r16 * 72 + 32 + g * 8];

      // PV: O^T[d = di*16+4g+j][q = r16] += V^T[d][kv] P^T[kv][q]
#pragma unroll
      for (int di = 0; di < 4; ++di) {
        int row = di * 16 + r16;
        bf16x8 vf0 = *(const bf16x8*)&Vs[cur][row * 64 + ((g ^ sx) * 8)];
        bf16x8 vf1 = *(const bf16x8*)&Vs[cur][row * 64 + (((4 + g) ^ sx) * 8)];
        oacc[di] = mfma16(vf0, pf0, oacc[di]);
        oacc[di] = mfma16(vf1, pf1, oacc[di]);
      }

      __syncthreads();  // next-tile stage complete (vmcnt drained) + buf reads done
      cur ^= 1;
    }

    // epilogue: O[q = q0+qloc][d = di*16+4g+j], packed u32 stores
    float linv = 1.0f / lrun;
    unsigned short* op = Om + (size_t)(b * S_LEN + q0 + qloc) * DM + h * HD;
#pragma unroll
    for (int di = 0; di < 4; ++di) {
      int d = di * 16 + 4 * g;
      unsigned lo = (unsigned)f2bf(oacc[di][0] * linv) |
                    ((unsigned)f2bf(oacc[di][1] * linv) << 16);
      unsigned hi2 = (unsigned)f2bf(oacc[di][2] * linv) |
                     ((unsigned)f2bf(oacc[di][3] * linv) << 16);
      *(unsigned*)(op + d) = lo;
      *(unsigned*)(op + d + 2) = hi2;
    }
  }
}

extern "C" void kernel_launch(void* const* d_in, const int* in_sizes, int n_in,
                              void* d_out, int out_size, void* d_ws, size_t ws_size,
                              hipStream_t stream) {
  (void)in_sizes; (void)n_in; (void)out_size; (void)ws_size;
  const float* x  = (const float*)d_in[0];
  const float* WQ = (const float*)d_in[1];
  const float* WK = (const float*)d_in[2];
  const float* WV = (const float*)d_in[3];
  const float* WO = (const float*)d_in[4];
  const float* bQ = (const float*)d_in[5];
  const float* bK = (const float*)d_in[6];
  const float* bV = (const float*)d_in[7];
  const float* bO = (const float*)d_in[8];

  char* ws = (char*)d_ws;
  unsigned short* xb  = (unsigned short*)(ws);               // 8 MiB (x bf16; reused as Vt later)
  unsigned short* wt  = (unsigned short*)(ws + (8u << 20));  // 8 MiB (Wq|Wk|Wv|Wo)^T
  unsigned short* qb  = (unsigned short*)(ws + (16u << 20)); // 24 MiB (Q|K|V bf16)
  unsigned short* hsb = (unsigned short*)(ws + (40u << 20)); // 8 MiB (attn out)
  unsigned short* vt  = xb;                                  // V^T overwrites xb after QKV GEMM

  cast_bf16_kernel<<<2048, 256, 0, stream>>>(x, xb);
  transpose_cast_kernel<<<dim3(32, 32, 4), 256, 0, stream>>>(WQ, WK, WV, WO, wt);
  // fused QKV projection: N = 3072
  gemm_bt_kernel<0><<<dim3(24, 32), 256, 0, stream>>>(
      xb, wt, (void*)qb, bQ, bK, bV, M_ROWS, 3072, DM);
  // V -> V^T  (x bf16 buffer no longer needed)
  vtrans_kernel<<<dim3(16, 32), 256, 0, stream>>>(qb + 8388608u, vt);
  attn_kernel<<<dim3(16, NH, BATCH), 256, 0, stream>>>(
      qb, qb + 4194304u, vt, hsb);
  // output projection: f32 out
  gemm_bt_kernel<1><<<dim3(8, 32), 256, 0, stream>>>(
      hsb, wt + 3u * 1048576u, d_out, bO, nullptr, nullptr, M_ROWS, DM, DM);
}